// Round 2
// baseline (2691.517 us; speedup 1.0000x reference)
//
#include <hip/hip_runtime.h>
#include <hip/hip_bf16.h>
#include <hip/hip_cooperative_groups.h>
#include <math.h>

namespace cg = cooperative_groups;

// Problem dims (compile-time)
constexpr int NB = 64;     // batch
constexpr int NT = 30;     // decode steps
constexpr int NS = 31;     // encoder positions
constexpr int NE = 128;    // embedding dim
constexpr int NU = 256;    // hidden
constexpr int NV = 32000;  // vocab
constexpr int NG = 4 * NU; // 1024 (gates)

__device__ __forceinline__ float sigmoidf_(float x) {
    return 1.0f / (1.0f + __expf(-x));
}

// ---------------------------------------------------------------------------
// keys[b,s,v] = sum_u memory[b,s,u] * W_mem[u,v]
// ---------------------------------------------------------------------------
__global__ __launch_bounds__(256) void keys_kernel(
    const float* __restrict__ memory, const float* __restrict__ W_mem,
    float* __restrict__ keys) {
    const int row0 = blockIdx.x * 8;   // row = b*NS + s, 1984 rows total
    const int u = threadIdx.x;
    __shared__ float mS[8][NU];
#pragma unroll
    for (int r = 0; r < 8; ++r) mS[r][u] = memory[(row0 + r) * NU + u];
    __syncthreads();
    float acc[8] = {0, 0, 0, 0, 0, 0, 0, 0};
#pragma unroll 4
    for (int v = 0; v < NU; ++v) {
        float w = W_mem[v * NU + u];
#pragma unroll
        for (int r = 0; r < 8; ++r) acc[r] += mS[r][v] * w;
    }
#pragma unroll
    for (int r = 0; r < 8; ++r) keys[(row0 + r) * NU + u] = acc[r];
}

// ---------------------------------------------------------------------------
// Generic fp32 64x64-tile GEMM, kc=32, 256 threads, 4x4 per thread.
// AMODE: 0 = A row m; 1 = A row idx[(m&63)*30 + (m>>6)] (emb gather, m=t*64+b);
//        2 = A row (m%30)*64 + m/30 (hc gather, out row m=b*30+t).
// C[m,n] = sum_k A[row(m)*lda+k]*B[k*ldb+n] + bias[n] + (m<addM ? add[m*ldc+n] : 0)
// ---------------------------------------------------------------------------
template <int AMODE>
__global__ __launch_bounds__(256) void gemm64(
    const float* __restrict__ A, int lda,
    const float* __restrict__ B, int ldb,
    float* __restrict__ C, int ldc, int K,
    const float* __restrict__ bias,
    const float* __restrict__ add, int addM,
    const int* __restrict__ idx)
{
    const int n0 = blockIdx.x * 64, m0 = blockIdx.y * 64;
    const int tid = threadIdx.x;
    const int tx = tid & 15, ty = tid >> 4;
    __shared__ float As[32][72];  // stride 72 floats = 288B (16B-aligned)
    __shared__ float Bs[32][64];
    float acc[4][4] = {};
    const int kq = tid & 7, r0 = tid >> 3;
    const int nq = tid & 15, kr0 = tid >> 4;

    for (int kb = 0; kb < K; kb += 32) {
#pragma unroll
        for (int p = 0; p < 2; ++p) {
            int r = r0 + p * 32;
            int m = m0 + r;
            int row;
            if (AMODE == 0) row = m;
            else if (AMODE == 1) row = idx[(m & 63) * 30 + (m >> 6)];
            else row = (m % 30) * 64 + (m / 30);
            float4 av = *(const float4*)(A + (size_t)row * lda + kb + kq * 4);
            As[kq * 4 + 0][r] = av.x;
            As[kq * 4 + 1][r] = av.y;
            As[kq * 4 + 2][r] = av.z;
            As[kq * 4 + 3][r] = av.w;
        }
#pragma unroll
        for (int p = 0; p < 2; ++p) {
            int kr = kr0 + p * 16;
            *(float4*)&Bs[kr][nq * 4] =
                *(const float4*)(B + (size_t)(kb + kr) * ldb + n0 + nq * 4);
        }
        __syncthreads();
#pragma unroll 8
        for (int k = 0; k < 32; ++k) {
            float4 a4 = *(const float4*)&As[k][ty * 4];
            float4 b4 = *(const float4*)&Bs[k][tx * 4];
            float am[4] = {a4.x, a4.y, a4.z, a4.w};
            float bn[4] = {b4.x, b4.y, b4.z, b4.w};
#pragma unroll
            for (int i = 0; i < 4; ++i)
#pragma unroll
                for (int j = 0; j < 4; ++j) acc[i][j] += am[i] * bn[j];
        }
        __syncthreads();
    }

    float4 bv = bias ? *(const float4*)(bias + n0 + tx * 4)
                     : make_float4(0.f, 0.f, 0.f, 0.f);
#pragma unroll
    for (int i = 0; i < 4; ++i) {
        int m = m0 + ty * 4 + i;
        float4 v;
        v.x = acc[i][0] + bv.x; v.y = acc[i][1] + bv.y;
        v.z = acc[i][2] + bv.z; v.w = acc[i][3] + bv.w;
        if (add && m < addM) {
            float4 a2 = *(const float4*)(add + (size_t)m * ldc + n0 + tx * 4);
            v.x += a2.x; v.y += a2.y; v.z += a2.z; v.w += a2.w;
        }
        *(float4*)(C + (size_t)m * ldc + n0 + tx * 4) = v;
    }
}

// ---------------------------------------------------------------------------
// hc slot 0 init: h = sample_h, ctx = 0
// ---------------------------------------------------------------------------
__global__ __launch_bounds__(256) void init_hc(const float* __restrict__ sh,
                                               float* __restrict__ hc) {
    int i = blockIdx.x * 256 + threadIdx.x;  // [0, 64*512)
    int b = i >> 9, k = i & 511;
    hc[i] = (k < NU) ? sh[b * NU + k] : 0.0f;
}

// ---------------------------------------------------------------------------
// Cooperative weight-stationary recurrence.
// Grid = 128 blocks x 256 threads. Block g owns u in {2g, 2g+1}.
// hc layout: [31 slots][64 b][512] with slot t+1 = (h_t | ctx_t), slot 0 = init.
// Per step: S1 (all blocks): z -> gates -> h;  sync;  S2 (blocks<64, b=g):
// scores/softmax/ctx;  sync.
// ---------------------------------------------------------------------------
__global__ __launch_bounds__(256) void recurrence_coop(
    const float* __restrict__ xz,       // [30][64][1024]  rows t*64+b
    const float* __restrict__ weff,     // [512][1024]
    const float* __restrict__ W_r,      // [256][1024]
    const float* __restrict__ sample_c, // [64][256]
    const float* __restrict__ memory,   // [64][31][256]
    const float* __restrict__ keys,     // [64][31][256]
    float* __restrict__ hc)             // [31][64][512]
{
    cg::grid_group gridg = cg::this_grid();
    const int g = blockIdx.x;          // 0..127
    const int tid = threadIdx.x;
    const int b = tid >> 2, gate = tid & 3;
    const int u0 = g * 2;

    __shared__ float WeffS[512][8];    // [k][gate*2+uu]
    __shared__ float WrS[256][8];
    __shared__ float zS[64][2][4];     // [b][uu][gate]
    __shared__ float cst[64][2];
    __shared__ float hS[256];
    __shared__ float spS[248];
    __shared__ float scS[31];

    for (int i = tid; i < 512 * 8; i += 256) {
        int k = i >> 3, j = i & 7;
        WeffS[k][j] = weff[(size_t)k * NG + (j >> 1) * NU + u0 + (j & 1)];
    }
    for (int i = tid; i < 256 * 8; i += 256) {
        int k = i >> 3, j = i & 7;
        WrS[k][j] = W_r[(size_t)k * NG + (j >> 1) * NU + u0 + (j & 1)];
    }
    if (tid < 128) {
        int bb = tid >> 1, uu = tid & 1;
        cst[bb][uu] = sample_c[bb * NU + u0 + uu];
    }
    __syncthreads();

    for (int t = 0; t < NT; ++t) {
        // ---- S1: z[b, 4 gates, 2 u's]; thread = (b, gate) ----
        const float* act = hc + (size_t)t * NB * 512 + b * 512;
        const float* xzr = xz + ((size_t)t * NB + b) * NG + gate * NU + u0;
        float acc0 = xzr[0], acc1 = xzr[1];
        const int klen = (t == 0) ? NU : 512;
        const float* Wp = (t == 0) ? &WrS[0][0] : &WeffS[0][0];
#pragma unroll 4
        for (int k = 0; k < klen; k += 4) {
            float4 a = *(const float4*)(act + k);
            const float* w = Wp + (size_t)k * 8 + gate * 2;
            acc0 += a.x * w[0];  acc1 += a.x * w[1];
            acc0 += a.y * w[8];  acc1 += a.y * w[9];
            acc0 += a.z * w[16]; acc1 += a.z * w[17];
            acc0 += a.w * w[24]; acc1 += a.w * w[25];
        }
        zS[b][0][gate] = acc0;
        zS[b][1][gate] = acc1;
        __syncthreads();

        if (tid < 128) {
            int bb = tid >> 1, uu = tid & 1;
            float zi = zS[bb][uu][0], zf = zS[bb][uu][1];
            float zg = zS[bb][uu][2], zo = zS[bb][uu][3];
            float c = sigmoidf_(zf) * cst[bb][uu] + sigmoidf_(zi) * tanhf(zg);
            cst[bb][uu] = c;
            hc[(size_t)(t + 1) * NB * 512 + bb * 512 + u0 + uu] =
                sigmoidf_(zo) * tanhf(c);
        }
        __threadfence();
        gridg.sync();

        // ---- S2: scores/softmax/context for batch b = g (blocks < 64) ----
        if (g < NB) {
            const int bb = g;
            hS[tid] = hc[(size_t)(t + 1) * NB * 512 + bb * 512 + tid];
            __syncthreads();
            if (tid < 248) {
                int s = tid >> 3, p = tid & 7;
                const float* hp = hS + p * 32;
                const float* kp = keys + ((size_t)bb * NS + s) * NU + p * 32;
                float sp = 0.f;
#pragma unroll 8
                for (int i = 0; i < 32; ++i) sp += hp[i] * kp[i];
                spS[tid] = sp;
            }
            __syncthreads();
            if (tid < NS) {
                float sc = 0.f;
#pragma unroll
                for (int p = 0; p < 8; ++p) sc += spS[tid * 8 + p];
                scS[tid] = sc;
            }
            __syncthreads();
            float mx = scS[0];
#pragma unroll
            for (int s = 1; s < NS; ++s) mx = fmaxf(mx, scS[s]);
            float sE = 0.f, ctx = 0.f;
            const float* memb = memory + (size_t)bb * NS * NU;
#pragma unroll 4
            for (int s = 0; s < NS; ++s) {
                float e = __expf(scS[s] - mx);
                sE += e;
                ctx += e * memb[s * NU + tid];
            }
            hc[(size_t)(t + 1) * NB * 512 + bb * 512 + NU + tid] = ctx / sE;
        }
        __threadfence();
        gridg.sync();
    }
}

// ---------------------------------------------------------------------------
// out[m, n] = attn_all[m, :] @ W_fc[:, n] + b_fc[n],  m = b*NT + t (fp32)
// ---------------------------------------------------------------------------
constexpr int BM = 128, BN = 128, KC = 32, KTOT = NU;

__global__ __launch_bounds__(256) void out_gemm(
    const float* __restrict__ A,    // [1920,256]
    const float* __restrict__ Wfc,  // [256,32000]
    const float* __restrict__ bfc,  // [32000]
    float* __restrict__ out)        // [1920,32000]
{
    const int n0 = blockIdx.x * BN;
    const int m0 = blockIdx.y * BM;
    const int tid = threadIdx.x;
    const int tx = tid & 15, ty = tid >> 4;

    __shared__ float As[KC][BM + 4];
    __shared__ float Bs[KC][BN];

    float acc[2][4][2][4] = {};

    const int kq = tid & 7,  r0 = tid >> 3;
    const int nq = tid & 31, kr0 = tid >> 5;

    for (int kb = 0; kb < KTOT; kb += KC) {
#pragma unroll
        for (int p = 0; p < 4; ++p) {
            int r = r0 + p * 32;
            float4 av = *(const float4*)(A + (size_t)(m0 + r) * KTOT + kb + kq * 4);
            As[kq * 4 + 0][r] = av.x;
            As[kq * 4 + 1][r] = av.y;
            As[kq * 4 + 2][r] = av.z;
            As[kq * 4 + 3][r] = av.w;
        }
#pragma unroll
        for (int p = 0; p < 4; ++p) {
            int kr = kr0 + p * 8;
            *(float4*)&Bs[kr][nq * 4] =
                *(const float4*)(Wfc + (size_t)(kb + kr) * NV + n0 + nq * 4);
        }
        __syncthreads();

#pragma unroll 4
        for (int k = 0; k < KC; ++k) {
            float4 a0 = *(const float4*)&As[k][ty * 4];
            float4 a1 = *(const float4*)&As[k][64 + ty * 4];
            float4 b0 = *(const float4*)&Bs[k][tx * 4];
            float4 b1 = *(const float4*)&Bs[k][64 + tx * 4];
            float am[2][4] = {{a0.x, a0.y, a0.z, a0.w}, {a1.x, a1.y, a1.z, a1.w}};
            float bv[2][4] = {{b0.x, b0.y, b0.z, b0.w}, {b1.x, b1.y, b1.z, b1.w}};
#pragma unroll
            for (int im = 0; im < 2; ++im)
#pragma unroll
                for (int i = 0; i < 4; ++i)
#pragma unroll
                    for (int jn = 0; jn < 2; ++jn)
#pragma unroll
                        for (int j = 0; j < 4; ++j)
                            acc[im][i][jn][j] += am[im][i] * bv[jn][j];
        }
        __syncthreads();
    }

    float4 bias[2];
    bias[0] = *(const float4*)(bfc + n0 + tx * 4);
    bias[1] = *(const float4*)(bfc + n0 + 64 + tx * 4);
#pragma unroll
    for (int im = 0; im < 2; ++im)
#pragma unroll
        for (int i = 0; i < 4; ++i) {
            int m = m0 + im * 64 + ty * 4 + i;
#pragma unroll
            for (int jn = 0; jn < 2; ++jn) {
                float4 v;
                float4 bb = bias[jn];
                v.x = acc[im][i][jn][0] + bb.x;
                v.y = acc[im][i][jn][1] + bb.y;
                v.z = acc[im][i][jn][2] + bb.z;
                v.w = acc[im][i][jn][3] + bb.w;
                *(float4*)(out + (size_t)m * NV + n0 + jn * 64 + tx * 4) = v;
            }
        }
}

// ---------------------------------------------------------------------------
extern "C" void kernel_launch(void* const* d_in, const int* in_sizes, int n_in,
                              void* d_out, int out_size, void* d_ws, size_t ws_size,
                              hipStream_t stream) {
    const int*   inputs   = (const int*)  d_in[0];
    const float* memory   = (const float*)d_in[1];
    const float* sample_h = (const float*)d_in[2];
    const float* sample_c = (const float*)d_in[3];
    const float* emb      = (const float*)d_in[4];
    const float* W_k      = (const float*)d_in[5];
    const float* W_r      = (const float*)d_in[6];
    const float* b_lstm   = (const float*)d_in[7];
    const float* W_mem    = (const float*)d_in[8];
    const float* W_attn   = (const float*)d_in[9];
    const float* W_fc     = (const float*)d_in[10];
    const float* b_fc     = (const float*)d_in[11];
    float* out = (float*)d_out;

    // workspace layout (floats)
    float* keys = (float*)d_ws;                        // 64*31*256   = 507904
    float* weff = keys + (size_t)NB * NS * NU;         // 512*1024    = 524288
    float* xz   = weff + (size_t)512 * NG;             // 1920*1024   = 1966080
    float* hc   = xz + (size_t)NB * NT * NG;           // 31*64*512   = 1015808
    float* attn = hc + (size_t)(NT + 1) * NB * 512;    // 1920*256    = 491520

    keys_kernel<<<(NB * NS) / 8, 256, 0, stream>>>(memory, W_mem, keys);

    // W_eff[0:256]   = W_attn[0:256] @ W_k[128:384,:] + W_r
    // W_eff[256:512] = W_attn[256:512] @ W_k[128:384,:]
    gemm64<0><<<dim3(NG / 64, 512 / 64), 256, 0, stream>>>(
        W_attn, NU, W_k + (size_t)NE * NG, NG, weff, NG, NU,
        nullptr, W_r, NU, nullptr);

    // xz[t*64+b, :] = emb[inputs[b,t]] @ W_k[0:128,:] + b_lstm
    gemm64<1><<<dim3(NG / 64, (NB * NT) / 64), 256, 0, stream>>>(
        emb, NE, W_k, NG, xz, NG, NE, b_lstm, nullptr, 0, inputs);

    init_hc<<<(NB * 512) / 256, 256, 0, stream>>>(sample_h, hc);

    {
        const float* a0 = xz; const float* a1 = weff; const float* a2 = W_r;
        const float* a3 = sample_c; const float* a4 = memory;
        const float* a5 = keys; float* a6 = hc;
        void* args[] = {&a0, &a1, &a2, &a3, &a4, &a5, &a6};
        hipLaunchCooperativeKernel((const void*)recurrence_coop, dim3(128),
                                   dim3(256), args, 0, stream);
    }

    // attn_all[b*30+t, :] = [h_t | ctx_t] @ W_attn
    gemm64<2><<<dim3(NU / 64, (NB * NT) / 64), 256, 0, stream>>>(
        hc + (size_t)NB * 512, 512, W_attn, NU, attn, NU, 512,
        nullptr, nullptr, 0, nullptr);

    out_gemm<<<dim3(NV / BN, (NB * NT) / BM), 256, 0, stream>>>(attn, W_fc,
                                                                b_fc, out);
}